// Round 4
// baseline (24118.320 us; speedup 1.0000x reference)
//
#include <hip/hip_runtime.h>
#include <hip/hip_cooperative_groups.h>

namespace cg = cooperative_groups;

#define BB 16
#define TT 2048
#define HIDN 896
#define HALFN 448
#define NBINS 256
#define NWG 112
#define NTHR 256
#define CPW 8
#define WSTR 904            /* sW padded ushort stride (2-way reads) */
#define SROW 896            /* sH stride; conflicts handled by XOR swizzle */

typedef __attribute__((ext_vector_type(8))) short short8;
typedef __attribute__((ext_vector_type(4))) float f32x4;

__device__ __forceinline__ unsigned short f2bf(float x) {
    unsigned int u = __float_as_uint(x);
    unsigned int r = u + 0x7FFFu + ((u >> 16) & 1u);
    return (unsigned short)(r >> 16);
}

// ---------------------------------------------------------------------------
// Persistent GRU scan, tag-in-value h exchange + cond prefetch pipeline.
// 112 WGs x 256 thr. WG g owns h-cols [8g,8g+8): 24 outputs x 16 batches.
// Wave0: MFMA tile (gates r,z; 16 jj). Wave1: tile (gate n; 8 real jj).
// Waves 2,3: cond/sig prefetchers (4-deep LDS ring, 2 steps write-ahead).
// h element u32 = (bf16 << 16) | (step & 0xffff); parity double-buffer.
// sH is XOR-swizzled: ushort off ^= (row&7)<<3  (16B granule).
// ---------------------------------------------------------------------------
__global__ __launch_bounds__(NTHR, 1)
void scan_kernel(const float* __restrict__ cond,
                 const int*   __restrict__ sig,
                 const int*   __restrict__ tcrs,
                 const float* __restrict__ Wc,
                 const float* __restrict__ Wf,
                 const float* __restrict__ Whh,
                 const float* __restrict__ b_ih,
                 const float* __restrict__ b_hh,
                 unsigned* __restrict__ htag,     // [2][16][896] u32
                 unsigned short* __restrict__ hc_out,
                 float* __restrict__ lasth)
{
    __shared__ unsigned short sW[32 * WSTR];   // 57,856 B
    __shared__ unsigned short sH[16 * SROW];   // 28,672 B (swizzled)
    __shared__ float sX[4][BB][3][CPW];        //  6,144 B cond ring
    __shared__ float sSg[4][BB][4];            //  1,024 B sig ring
    __shared__ float rz[2][BB][CPW];           //  1,024 B

    const int tid  = threadIdx.x;
    const int wg   = blockIdx.x;
    const int col0 = wg * CPW;

    // ---- one-time: W slice -> LDS bf16 ----
    for (int idx = tid; idx < 32 * HIDN; idx += NTHR) {
        int jj = idx & 31, k = idx >> 5;
        unsigned short wv = 0;
        if (jj < 24)
            wv = f2bf(Whh[(size_t)k * 2688 + (jj >> 3) * HIDN + col0 + (jj & 7)]);
        sW[jj * WSTR + k] = wv;
    }
    // ---- zero sH (h0 = 0) ----
    for (int idx = tid; idx < (16 * SROW) / 2; idx += NTHR)
        ((unsigned*)sH)[idx] = 0;
    // ---- clear own tag slice, both parities (replay safety) ----
    {
        int p = tid >> 7, r = tid & 127;
        int b = r >> 3, c = r & 7;
        htag[p * (BB * HIDN) + b * HIDN + col0 + c] = 0x0000FFFFu;
    }

    // ---- roles ----
    const int w  = tid >> 6;      // wave 0..3
    const int l  = tid & 63;
    const int hi = l >> 4;
    int gate = 0, c = 0;
    if (w == 0) { gate = (l & 15) >> 3; c = l & 7; }
    else if (w == 1) { gate = 2; c = l & 15; }
    const bool xrole = (w == 0) || (w == 1 && c < 8);
    const int col  = col0 + (c & 7);
    const int gcol = gate * HIDN + col;

    float wp0 = 0.f, wp1 = 0.f, wp2 = 0.f, bi = 0.f, bh = 0.f;
    if (xrole) {
        if (col < HALFN) {
            wp0 = Wc[gate * HALFN + col];
            wp1 = Wc[1344 + gate * HALFN + col];
        } else {
            int ck = col - HALFN;
            wp0 = Wf[gate * HALFN + ck];
            wp1 = Wf[1344 + gate * HALFN + ck];
            wp2 = Wf[2688 + gate * HALFN + ck];
        }
        bi = b_ih[gcol];
        bh = b_hh[gcol];
    }
    float hp[4] = {0.f, 0.f, 0.f, 0.f};

    // ---- prefetch lane mapping (waves 2,3) ----
    const float inv = 1.f / 127.5f;
    const int pfi = tid - 128;
    const bool cok = (pfi >= 0 && pfi < 96);
    const bool sok = (pfi >= 0 && pfi < 48);
    int cb = 0, cg2 = 0, cq = 0, sb = 0, sj = 0;
    if (cok) { cb = pfi / 6; int rem = pfi % 6; cg2 = rem >> 1; cq = rem & 1; }
    if (sok) { sb = pfi / 3; sj = pfi % 3; }

    float4 pfc = make_float4(0.f, 0.f, 0.f, 0.f);
    float  pfs = 0.f;
    if (w >= 2) {
        // fill ring slots 0,1 directly; slot-2 data held in regs
        for (int s = 0; s < 2; ++s) {
            if (cok) {
                float4 v = *(const float4*)(cond +
                    ((size_t)(cb * TT + s) * 3 + cg2) * HIDN + col0 + cq * 4);
                *(float4*)&sX[s][cb][cg2][cq * 4] = v;
            }
            if (sok) {
                int iv = (sj < 2) ? sig[((size_t)sb * TT + s) * 2 + sj]
                                  : tcrs[(size_t)sb * TT + s];
                sSg[s][sb][sj] = (float)iv * inv - 1.f;
            }
        }
        if (cok)
            pfc = *(const float4*)(cond +
                ((size_t)(cb * TT + 2) * 3 + cg2) * HIDN + col0 + cq * 4);
        if (sok) {
            int iv = (sj < 2) ? sig[((size_t)sb * TT + 2) * 2 + sj]
                              : tcrs[(size_t)sb * TT + 2];
            pfs = (float)iv * inv - 1.f;
        }
    }

    __syncthreads();
    cg::this_grid().sync();        // clears + ring slots visible

    const int pb = tid >> 4;       // poll: batch row 0..15
    const int pp = tid & 15;       // poll: u64 lane offset
    const int swzw = (pb & 7) << 3;       // staging write swizzle (ushorts)

    for (int t = 0; t < TT; ++t) {
        if (t > 0) {
            // ---- poll h(t) by tag; stage into swizzled sH ----
            const unsigned tagv = (unsigned)(t & 0xffff);
            const unsigned long long* hb =
                (const unsigned long long*)(htag + (t & 1) * (BB * HIDN));
            unsigned long long v[28];
            #pragma unroll
            for (int i = 0; i < 28; ++i)
                v[i] = __hip_atomic_load(&hb[pb * 448 + pp + i * 16],
                                         __ATOMIC_RELAXED, __HIP_MEMORY_SCOPE_AGENT);
            unsigned pend = 0;
            #pragma unroll
            for (int i = 0; i < 28; ++i) {
                bool ok = (((unsigned)v[i] & 0xffffu) == tagv) &
                          (((unsigned)(v[i] >> 32) & 0xffffu) == tagv);
                int pos = pp + i * 16;
                if (ok)
                    *(unsigned*)&sH[pb * SROW + ((2 * pos) ^ swzw)] =
                        ((unsigned)(v[i] >> 16) & 0xffffu) | ((unsigned)(v[i] >> 48) << 16);
                else
                    pend |= 1u << i;
            }
            while (pend) {
                __builtin_amdgcn_s_sleep(2);
                unsigned np = 0;
                #pragma unroll
                for (int i = 0; i < 28; ++i) {
                    if (pend & (1u << i)) {
                        unsigned long long vv =
                            __hip_atomic_load(&hb[pb * 448 + pp + i * 16],
                                              __ATOMIC_RELAXED, __HIP_MEMORY_SCOPE_AGENT);
                        bool ok = (((unsigned)vv & 0xffffu) == tagv) &
                                  (((unsigned)(vv >> 32) & 0xffffu) == tagv);
                        int pos = pp + i * 16;
                        if (ok)
                            *(unsigned*)&sH[pb * SROW + ((2 * pos) ^ swzw)] =
                                ((unsigned)(vv >> 16) & 0xffffu) | ((unsigned)(vv >> 48) << 16);
                        else
                            np |= 1u << i;
                    }
                }
                pend = np;
            }
        }
        __syncthreads();                       // sync1: sH(t), sX[t&3] ready

        float xv[4];
        f32x4 acc;
        if (w < 2) {
            // x values from LDS ring (cheap, hides under MFMA)
            if (xrole) {
                int slot = t & 3;
                #pragma unroll
                for (int r = 0; r < 4; ++r) {
                    int b = hi * 4 + r;
                    xv[r] = sX[slot][b][gate][c & 7] + bi
                          + sSg[slot][b][0] * wp0
                          + sSg[slot][b][1] * wp1
                          + sSg[slot][b][2] * wp2;
                }
            }
            // ---- gh = h @ W : 28 MFMAs, 4 independent chains ----
            const int row = l & 15;
            const int xb  = (row & 7) << 3;
            const unsigned short* pa = sH + row * SROW + ((hi * 8) ^ (xb & 0x18));
            const int xb5 = xb & 0x20;
            const unsigned short* pw = &sW[((w << 4) + row) * WSTR + hi * 8];
            f32x4 a0 = {0.f,0.f,0.f,0.f}, a1 = {0.f,0.f,0.f,0.f};
            f32x4 a2 = {0.f,0.f,0.f,0.f}, a3 = {0.f,0.f,0.f,0.f};
            #pragma unroll
            for (int ks = 0; ks < 28; ks += 4) {
                short8 av0 = *(const short8*)(pa + (((ks+0) * 32) ^ xb5));
                short8 bv0 = *(const short8*)(pw + (ks+0) * 32);
                a0 = __builtin_amdgcn_mfma_f32_16x16x32_bf16(av0, bv0, a0, 0, 0, 0);
                short8 av1 = *(const short8*)(pa + (((ks+1) * 32) ^ xb5));
                short8 bv1 = *(const short8*)(pw + (ks+1) * 32);
                a1 = __builtin_amdgcn_mfma_f32_16x16x32_bf16(av1, bv1, a1, 0, 0, 0);
                short8 av2 = *(const short8*)(pa + (((ks+2) * 32) ^ xb5));
                short8 bv2 = *(const short8*)(pw + (ks+2) * 32);
                a2 = __builtin_amdgcn_mfma_f32_16x16x32_bf16(av2, bv2, a2, 0, 0, 0);
                short8 av3 = *(const short8*)(pa + (((ks+3) * 32) ^ xb5));
                short8 bv3 = *(const short8*)(pw + (ks+3) * 32);
                a3 = __builtin_amdgcn_mfma_f32_16x16x32_bf16(av3, bv3, a3, 0, 0, 0);
            }
            acc = (a0 + a1) + (a2 + a3);
            if (w == 0) {
                #pragma unroll
                for (int r = 0; r < 4; ++r) {
                    float g = xv[r] + acc[r] + bh;
                    rz[gate][hi * 4 + r][c] = 1.f / (1.f + __expf(-g));
                }
            }
        } else {
            // ---- prefetch pipeline: write step t+2 ring slot, load t+3 ----
            int wslot = (t + 2) & 3;
            if (cok) *(float4*)&sX[wslot][cb][cg2][cq * 4] = pfc;
            if (sok) sSg[wslot][sb][sj] = pfs;
            int tn = (t + 3 < TT) ? t + 3 : TT - 1;
            if (cok)
                pfc = *(const float4*)(cond +
                    ((size_t)(cb * TT + tn) * 3 + cg2) * HIDN + col0 + cq * 4);
            if (sok) {
                int iv = (sj < 2) ? sig[((size_t)sb * TT + tn) * 2 + sj]
                                  : tcrs[(size_t)sb * TT + tn];
                pfs = (float)iv * inv - 1.f;
            }
        }
        __syncthreads();                       // sync2: rz ready

        if (w == 1) {
            unsigned myu[4];
            if (c < 8) {
                const unsigned tago = (unsigned)((t + 1) & 0xffff);
                unsigned* hdst = htag + ((t + 1) & 1) * (BB * HIDN);
                #pragma unroll
                for (int r = 0; r < 4; ++r) {
                    int b = hi * 4 + r;
                    float rr = rz[0][b][c];
                    float zz = rz[1][b][c];
                    float a2v = xv[r] + rr * (acc[r] + bh);
                    float e = __expf(-2.f * a2v);
                    float n = (1.f - e) / (1.f + e);
                    float hn = (1.f - zz) * n + zz * hp[r];
                    hp[r] = hn;
                    myu[r] = ((unsigned)f2bf(hn) << 16) | tago;
                    if (t < TT - 1)
                        __hip_atomic_store(&hdst[b * HIDN + col], myu[r],
                                           __ATOMIC_RELAXED, __HIP_MEMORY_SCOPE_AGENT);
                    else
                        lasth[(size_t)b * HIDN + col] = hn;
                }
            }
            if (wg < 56 && c < 8) {
                #pragma unroll
                for (int r = 0; r < 4; ++r) {
                    unsigned other = (unsigned)__shfl((int)myu[r], l + 1);
                    if (!(c & 1)) {
                        int b = hi * 4 + r;
                        *(unsigned*)(hc_out + ((size_t)b * TT + t) * HALFN + col) =
                            (myu[r] >> 16) | (other & 0xffff0000u);
                    }
                }
            }
        }
    }
}

// ---------------------------------------------------------------------------
// Head GEMM: C(M x N) = [relu](A_bf16(M x 448) @ Bw(448 x N) + bias)
// ---------------------------------------------------------------------------
template<int RELU_BF16>
__global__ __launch_bounds__(256)
void head_gemm(const unsigned short* __restrict__ A,
               const float* __restrict__ Bw,
               const float* __restrict__ bias,
               unsigned short* __restrict__ Cb,
               float* __restrict__ Cf,
               int N)
{
    const int K = 448;
    __shared__ float As[32][68];
    __shared__ float Bs[32][68];
    const int tid = threadIdx.x;
    const int tx = tid & 15;
    const int ty = tid >> 4;
    const int bm = blockIdx.x * 64;
    const int bn = blockIdx.y * 64;

    float acc[4][4] = {};

    for (int k0 = 0; k0 < K; k0 += 32) {
        #pragma unroll
        for (int it = 0; it < 2; ++it) {
            int idx = tid + it * 256;
            int m   = idx >> 3;
            int k4  = idx & 7;
            ushort4 av = *(const ushort4*)(A + (size_t)(bm + m) * K + k0 + k4 * 4);
            As[k4 * 4 + 0][m] = __uint_as_float((unsigned)av.x << 16);
            As[k4 * 4 + 1][m] = __uint_as_float((unsigned)av.y << 16);
            As[k4 * 4 + 2][m] = __uint_as_float((unsigned)av.z << 16);
            As[k4 * 4 + 3][m] = __uint_as_float((unsigned)av.w << 16);
        }
        #pragma unroll
        for (int it = 0; it < 2; ++it) {
            int idx = tid + it * 256;
            int k   = idx >> 4;
            int n4  = idx & 15;
            *(float4*)&Bs[k][n4 * 4] =
                *(const float4*)(Bw + (size_t)(k0 + k) * N + bn + n4 * 4);
        }
        __syncthreads();
        #pragma unroll
        for (int k = 0; k < 32; ++k) {
            float4 a4 = *(float4*)&As[k][ty * 4];
            float4 b4 = *(float4*)&Bs[k][tx * 4];
            float ar[4] = {a4.x, a4.y, a4.z, a4.w};
            float br[4] = {b4.x, b4.y, b4.z, b4.w};
            #pragma unroll
            for (int i = 0; i < 4; ++i)
                #pragma unroll
                for (int j = 0; j < 4; ++j)
                    acc[i][j] = fmaf(ar[i], br[j], acc[i][j]);
        }
        __syncthreads();
    }

    float4 bsv = *(const float4*)(bias + bn + tx * 4);
    float bb[4] = {bsv.x, bsv.y, bsv.z, bsv.w};
    #pragma unroll
    for (int i = 0; i < 4; ++i) {
        int row = bm + ty * 4 + i;
        float v[4];
        #pragma unroll
        for (int j = 0; j < 4; ++j) v[j] = acc[i][j] + bb[j];
        if (RELU_BF16) {
            ushort4 o;
            o.x = f2bf(fmaxf(v[0], 0.f));
            o.y = f2bf(fmaxf(v[1], 0.f));
            o.z = f2bf(fmaxf(v[2], 0.f));
            o.w = f2bf(fmaxf(v[3], 0.f));
            *(ushort4*)(Cb + (size_t)row * N + bn + tx * 4) = o;
        } else {
            float4 o = make_float4(v[0], v[1], v[2], v[3]);
            *(float4*)(Cf + (size_t)row * N + bn + tx * 4) = o;
        }
    }
}

// ---------------------------------------------------------------------------
extern "C" void kernel_launch(void* const* d_in, const int* in_sizes, int n_in,
                              void* d_out, int out_size, void* d_ws, size_t ws_size,
                              hipStream_t stream)
{
    const float* cond = (const float*)d_in[0];
    const int*   sig  = (const int*)d_in[1];
    const int*   tcrs = (const int*)d_in[2];
    const float* Wc   = (const float*)d_in[3];
    const float* Wf   = (const float*)d_in[4];
    const float* Whh  = (const float*)d_in[5];
    const float* bih  = (const float*)d_in[6];
    const float* bhh  = (const float*)d_in[7];
    const float* W1c  = (const float*)d_in[8];
    const float* b1c  = (const float*)d_in[9];
    const float* W2c  = (const float*)d_in[10];
    const float* b2c  = (const float*)d_in[11];
    const float* W1f  = (const float*)d_in[12];
    const float* b1f  = (const float*)d_in[13];
    const float* W2f  = (const float*)d_in[14];
    const float* b2f  = (const float*)d_in[15];

    char* ws = (char*)d_ws;
    unsigned* htag       = (unsigned*)ws;                        // 114,688 B
    unsigned short* hc   = (unsigned short*)(ws + 114688);       // 29,360,128 B
    unsigned short* hid1 = (unsigned short*)(ws + 114688 + 29360128);

    float* outc  = (float*)d_out;
    float* outf  = outc + (size_t)BB * TT * NBINS;
    float* lasth = outc + 2 * (size_t)BB * TT * NBINS;

    void* args[] = {(void*)&cond, (void*)&sig, (void*)&tcrs, (void*)&Wc, (void*)&Wf,
                    (void*)&Whh, (void*)&bih, (void*)&bhh,
                    (void*)&htag, (void*)&hc, (void*)&lasth};
    hipLaunchCooperativeKernel((void*)scan_kernel, dim3(NWG), dim3(NTHR),
                               args, 0, stream);

    dim3 blk(256);
    head_gemm<1><<<dim3(512, 7), blk, 0, stream>>>(hc,   W1c, b1c, hid1, nullptr, 448);
    head_gemm<0><<<dim3(512, 4), blk, 0, stream>>>(hid1, W2c, b2c, nullptr, outc, 256);
    head_gemm<1><<<dim3(512, 7), blk, 0, stream>>>(hc,   W1f, b1f, hid1, nullptr, 448);
    head_gemm<0><<<dim3(512, 4), blk, 0, stream>>>(hid1, W2f, b2f, nullptr, outf, 256);
}

// Round 5
// 9196.238 us; speedup vs baseline: 2.6226x; 2.6226x over previous
//
#include <hip/hip_runtime.h>
#include <hip/hip_cooperative_groups.h>

namespace cg = cooperative_groups;

#define BB 16
#define TT 2048
#define HIDN 896
#define HALFN 448
#define NBINS 256
#define NWG 224
#define NTHR 64
#define SROW 904            /* sH padded ushort stride */
#define WSTR 904            /* sW padded ushort stride */

typedef __attribute__((ext_vector_type(8))) short short8;
typedef __attribute__((ext_vector_type(4))) float f32x4;

__device__ __forceinline__ unsigned short f2bf(float x) {
    unsigned int u = __float_as_uint(x);
    unsigned int r = u + 0x7FFFu + ((u >> 16) & 1u);
    return (unsigned short)(r >> 16);
}

// ---------------------------------------------------------------------------
// Persistent GRU scan. 224 WGs x 1 wave (64 thr). WG g owns h-cols [4g,4g+4).
// Lane (hi=l>>4, jj=l&15): jj<12 -> gate=jj>>2, c=jj&3; computes gh for
// batches hi*4..hi*4+3 via one 16x16 MFMA tile (K=896, 28 MFMAs, 4 chains).
// Exchange: h u64 per (WG,batch) in hx[2][224][16]; slots[224] step counters.
// K-sliced (4 x 224 cols): wait slice / load slice pipelined, no syncthreads.
// r/z via __shfl (single wave). hc_out stores after publish (off drain).
// ---------------------------------------------------------------------------
__global__ __launch_bounds__(NTHR, 1)
void scan_kernel(const float* __restrict__ cond,
                 const int*   __restrict__ sig,
                 const int*   __restrict__ tcrs,
                 const float* __restrict__ Wc,
                 const float* __restrict__ Wf,
                 const float* __restrict__ Whh,
                 const float* __restrict__ b_ih,
                 const float* __restrict__ b_hh,
                 unsigned long long* __restrict__ hx,   // [2][224][16] u64
                 int* __restrict__ slots,               // [224]
                 unsigned short* __restrict__ hc_out,
                 float* __restrict__ lasth)
{
    __shared__ unsigned short sW[16 * WSTR];   // 28,928 B
    __shared__ unsigned short sH[16 * SROW];   // 28,928 B

    const int tid  = threadIdx.x;
    const int wg   = blockIdx.x;
    const int col0 = wg * 4;

    // ---- one-time: W slice -> LDS bf16 (cols 12..15 zero) ----
    for (int idx = tid; idx < 16 * HIDN; idx += NTHR) {
        int j2 = idx & 15, k = idx >> 4;
        unsigned short wv = 0;
        if (j2 < 12)
            wv = f2bf(Whh[(size_t)k * 2688 + (j2 >> 2) * HIDN + col0 + (j2 & 3)]);
        sW[j2 * WSTR + k] = wv;
    }
    // zero sH (h0 = 0)
    for (int idx = tid; idx < (16 * SROW) / 2; idx += NTHR)
        ((unsigned*)sH)[idx] = 0;
    if (tid == 0)
        __hip_atomic_store(&slots[wg], 0, __ATOMIC_RELAXED, __HIP_MEMORY_SCOPE_AGENT);

    // ---- lane roles ----
    const int l  = tid;
    const int jj = l & 15;
    const int hi = l >> 4;
    const bool xrole = jj < 12;
    const int gate = (jj >> 2) & 3;
    const int cc   = jj & 3;
    const int col  = col0 + cc;

    float wp0 = 0.f, wp1 = 0.f, wp2 = 0.f, bi = 0.f, bh = 0.f;
    if (xrole) {
        if (col < HALFN) {
            wp0 = Wc[gate * HALFN + col];
            wp1 = Wc[1344 + gate * HALFN + col];
        } else {
            int ck = col - HALFN;
            wp0 = Wf[gate * HALFN + ck];
            wp1 = Wf[1344 + gate * HALFN + ck];
            wp2 = Wf[2688 + gate * HALFN + ck];
        }
        bi = b_ih[gate * HIDN + col];
        bh = b_hh[gate * HIDN + col];
    }
    float hp[4] = {0.f, 0.f, 0.f, 0.f};

    __syncthreads();
    cg::this_grid().sync();          // slot clears visible grid-wide

    const float inv = 1.f / 127.5f;
    const unsigned long long* s64 = (const unsigned long long*)slots;
    const int srcr = (l & 48) | cc;        // gate0 lane, same hi
    const int srcz = (l & 48) | 4 | cc;    // gate1 lane, same hi

#define WAITS(s) { bool ok_;                                                   \
    for (;;) {                                                                 \
        ok_ = true;                                                            \
        if (l < 28) {                                                          \
            unsigned long long a_ = __hip_atomic_load(&s64[28*(s) + l],        \
                __ATOMIC_RELAXED, __HIP_MEMORY_SCOPE_AGENT);                   \
            ok_ = ((int)(a_ & 0xffffffffu) >= t) & ((int)(a_ >> 32) >= t);     \
        }                                                                      \
        if (__all(ok_)) break;                                                 \
        __builtin_amdgcn_s_sleep(1);                                           \
    }                                                                          \
    asm volatile("" ::: "memory"); }

#define LOADS(s, V) _Pragma("unroll")                                          \
    for (int i_ = 0; i_ < 14; ++i_)                                            \
        V[i_] = __hip_atomic_load(&hb[(size_t)((56*(s)) + hi*14 + i_)*16 + jj],\
            __ATOMIC_RELAXED, __HIP_MEMORY_SCOPE_AGENT);

#define STAGES(s, V) _Pragma("unroll")                                         \
    for (int i_ = 0; i_ < 14; ++i_)                                            \
        *(unsigned long long*)&sH[jj * SROW + ((56*(s)) + hi*14 + i_)*4] = V[i_];

#define MFMAS(s) _Pragma("unroll")                                             \
    for (int q_ = 0; q_ < 7; ++q_) {                                           \
        int ks_ = (s)*7 + q_;                                                  \
        short8 av_ = *(const short8*)&sH[jj * SROW + hi * 8 + ks_ * 32];       \
        short8 bv_ = *(const short8*)&sW[jj * WSTR + hi * 8 + ks_ * 32];       \
        ch[(7*(s) + q_) & 3] =                                                 \
            __builtin_amdgcn_mfma_f32_16x16x32_bf16(av_, bv_, ch[(7*(s)+q_)&3],\
                                                    0, 0, 0);                  \
    }

    for (int t = 0; t < TT; ++t) {
        // ---- x_t loads (issued early; consumed after MFMA) ----
        float xc[4], sg0[4], sg1[4], sg2[4];
        if (xrole) {
            #pragma unroll
            for (int r = 0; r < 4; ++r) {
                int b = hi * 4 + r;
                size_t bt = (size_t)b * TT + t;
                xc[r]  = cond[(bt * 3 + gate) * HIDN + col];
                sg0[r] = (float)sig[bt * 2 + 0] * inv - 1.f;
                sg1[r] = (float)sig[bt * 2 + 1] * inv - 1.f;
                sg2[r] = (float)tcrs[bt] * inv - 1.f;
            }
        } else {
            xc[0]=xc[1]=xc[2]=xc[3]=0.f;
            sg0[0]=sg0[1]=sg0[2]=sg0[3]=0.f;
            sg1[0]=sg1[1]=sg1[2]=sg1[3]=0.f;
            sg2[0]=sg2[1]=sg2[2]=sg2[3]=0.f;
        }

        f32x4 ch[4] = {};
        if (t > 0) {
            const unsigned long long* hb = hx + (size_t)(t & 1) * 3584;
            unsigned long long va[14], vb[14];
            WAITS(0); LOADS(0, va);
            WAITS(1); LOADS(1, vb);
            STAGES(0, va); MFMAS(0);
            WAITS(2); LOADS(2, va);
            STAGES(1, vb); MFMAS(1);
            WAITS(3); LOADS(3, vb);
            STAGES(2, va); MFMAS(2);
            STAGES(3, vb); MFMAS(3);
        } else {
            MFMAS(0); MFMAS(1); MFMAS(2); MFMAS(3);
        }

        f32x4 acc = (ch[0] + ch[1]) + (ch[2] + ch[3]);

        // ---- gates: r,z on gate0/1 lanes; shfl to gate2 lanes ----
        float xv[4], sigv[4];
        #pragma unroll
        for (int r = 0; r < 4; ++r) {
            xv[r]   = xc[r] + bi + sg0[r]*wp0 + sg1[r]*wp1 + sg2[r]*wp2;
            sigv[r] = 1.f / (1.f + __expf(-(xv[r] + acc[r] + bh)));
        }
        float rr[4], zz[4];
        #pragma unroll
        for (int r = 0; r < 4; ++r) {
            rr[r] = __shfl(sigv[r], srcr);
            zz[r] = __shfl(sigv[r], srcz);
        }
        unsigned short hbits[4] = {0, 0, 0, 0};
        if (jj >= 8 && jj < 12) {
            #pragma unroll
            for (int r = 0; r < 4; ++r) {
                float a2v = xv[r] + rr[r] * (acc[r] + bh);
                float e = __expf(-2.f * a2v);
                float n = (1.f - e) / (1.f + e);
                float hn = (1.f - zz[r]) * n + zz[r] * hp[r];
                hp[r] = hn;
                hbits[r] = f2bf(hn);
                if (t == TT - 1)
                    lasth[(size_t)(hi * 4 + r) * HIDN + col] = hn;
            }
        }
        // ---- pack 4 cols -> u64 per batch, store, drain, publish ----
        unsigned pp32[4];
        unsigned long long hv64[4];
        #pragma unroll
        for (int r = 0; r < 4; ++r) {
            int o1 = __shfl_xor((int)(unsigned)hbits[r], 1);
            unsigned p = ((unsigned)hbits[r] & 0xffffu) | ((unsigned)o1 << 16);
            pp32[r] = p;
            int o2 = __shfl_xor((int)p, 2);
            hv64[r] = (unsigned long long)p | ((unsigned long long)(unsigned)o2 << 32);
        }
        unsigned long long* hd = hx + (size_t)((t + 1) & 1) * 3584;
        if (jj == 8) {
            #pragma unroll
            for (int r = 0; r < 4; ++r)
                __hip_atomic_store(&hd[wg * 16 + hi * 4 + r], hv64[r],
                                   __ATOMIC_RELAXED, __HIP_MEMORY_SCOPE_AGENT);
        }
        asm volatile("s_waitcnt vmcnt(0)" ::: "memory");
        if (tid == 0)
            __hip_atomic_store(&slots[wg], t + 1, __ATOMIC_RELAXED, __HIP_MEMORY_SCOPE_AGENT);

        // ---- post-publish: history write (off critical path) ----
        if (wg < 112 && jj >= 8 && jj < 12 && !(jj & 1)) {
            unsigned* hc32 = (unsigned*)hc_out;
            #pragma unroll
            for (int r = 0; r < 4; ++r)
                hc32[((size_t)(hi * 4 + r) * TT + t) * 224 + wg * 2 + ((jj - 8) >> 1)] = pp32[r];
        }
    }
#undef WAITS
#undef LOADS
#undef STAGES
#undef MFMAS
}

// ---------------------------------------------------------------------------
// Head GEMM: C(M x N) = [relu](A_bf16(M x 448) @ Bw(448 x N) + bias)
// ---------------------------------------------------------------------------
template<int RELU_BF16>
__global__ __launch_bounds__(256)
void head_gemm(const unsigned short* __restrict__ A,
               const float* __restrict__ Bw,
               const float* __restrict__ bias,
               unsigned short* __restrict__ Cb,
               float* __restrict__ Cf,
               int N)
{
    const int K = 448;
    __shared__ float As[32][68];
    __shared__ float Bs[32][68];
    const int tid = threadIdx.x;
    const int tx = tid & 15;
    const int ty = tid >> 4;
    const int bm = blockIdx.x * 64;
    const int bn = blockIdx.y * 64;

    float acc[4][4] = {};

    for (int k0 = 0; k0 < K; k0 += 32) {
        #pragma unroll
        for (int it = 0; it < 2; ++it) {
            int idx = tid + it * 256;
            int m   = idx >> 3;
            int k4  = idx & 7;
            ushort4 av = *(const ushort4*)(A + (size_t)(bm + m) * K + k0 + k4 * 4);
            As[k4 * 4 + 0][m] = __uint_as_float((unsigned)av.x << 16);
            As[k4 * 4 + 1][m] = __uint_as_float((unsigned)av.y << 16);
            As[k4 * 4 + 2][m] = __uint_as_float((unsigned)av.z << 16);
            As[k4 * 4 + 3][m] = __uint_as_float((unsigned)av.w << 16);
        }
        #pragma unroll
        for (int it = 0; it < 2; ++it) {
            int idx = tid + it * 256;
            int k   = idx >> 4;
            int n4  = idx & 15;
            *(float4*)&Bs[k][n4 * 4] =
                *(const float4*)(Bw + (size_t)(k0 + k) * N + bn + n4 * 4);
        }
        __syncthreads();
        #pragma unroll
        for (int k = 0; k < 32; ++k) {
            float4 a4 = *(float4*)&As[k][ty * 4];
            float4 b4 = *(float4*)&Bs[k][tx * 4];
            float ar[4] = {a4.x, a4.y, a4.z, a4.w};
            float br[4] = {b4.x, b4.y, b4.z, b4.w};
            #pragma unroll
            for (int i = 0; i < 4; ++i)
                #pragma unroll
                for (int j = 0; j < 4; ++j)
                    acc[i][j] = fmaf(ar[i], br[j], acc[i][j]);
        }
        __syncthreads();
    }

    float4 bsv = *(const float4*)(bias + bn + tx * 4);
    float bb[4] = {bsv.x, bsv.y, bsv.z, bsv.w};
    #pragma unroll
    for (int i = 0; i < 4; ++i) {
        int row = bm + ty * 4 + i;
        float v[4];
        #pragma unroll
        for (int j = 0; j < 4; ++j) v[j] = acc[i][j] + bb[j];
        if (RELU_BF16) {
            ushort4 o;
            o.x = f2bf(fmaxf(v[0], 0.f));
            o.y = f2bf(fmaxf(v[1], 0.f));
            o.z = f2bf(fmaxf(v[2], 0.f));
            o.w = f2bf(fmaxf(v[3], 0.f));
            *(ushort4*)(Cb + (size_t)row * N + bn + tx * 4) = o;
        } else {
            float4 o = make_float4(v[0], v[1], v[2], v[3]);
            *(float4*)(Cf + (size_t)row * N + bn + tx * 4) = o;
        }
    }
}

// ---------------------------------------------------------------------------
extern "C" void kernel_launch(void* const* d_in, const int* in_sizes, int n_in,
                              void* d_out, int out_size, void* d_ws, size_t ws_size,
                              hipStream_t stream)
{
    const float* cond = (const float*)d_in[0];
    const int*   sig  = (const int*)d_in[1];
    const int*   tcrs = (const int*)d_in[2];
    const float* Wc   = (const float*)d_in[3];
    const float* Wf   = (const float*)d_in[4];
    const float* Whh  = (const float*)d_in[5];
    const float* bih  = (const float*)d_in[6];
    const float* bhh  = (const float*)d_in[7];
    const float* W1c  = (const float*)d_in[8];
    const float* b1c  = (const float*)d_in[9];
    const float* W2c  = (const float*)d_in[10];
    const float* b2c  = (const float*)d_in[11];
    const float* W1f  = (const float*)d_in[12];
    const float* b1f  = (const float*)d_in[13];
    const float* W2f  = (const float*)d_in[14];
    const float* b2f  = (const float*)d_in[15];

    char* ws = (char*)d_ws;
    int* slots               = (int*)ws;                         // 896 B (pad 4K)
    unsigned long long* hx   = (unsigned long long*)(ws + 4096); // 57,344 B
    unsigned short* hc       = (unsigned short*)(ws + 65536);    // 29,360,128 B
    unsigned short* hid1     = (unsigned short*)(ws + 65536 + 29360128);

    float* outc  = (float*)d_out;
    float* outf  = outc + (size_t)BB * TT * NBINS;
    float* lasth = outc + 2 * (size_t)BB * TT * NBINS;

    void* args[] = {(void*)&cond, (void*)&sig, (void*)&tcrs, (void*)&Wc, (void*)&Wf,
                    (void*)&Whh, (void*)&bih, (void*)&bhh,
                    (void*)&hx, (void*)&slots, (void*)&hc, (void*)&lasth};
    hipLaunchCooperativeKernel((void*)scan_kernel, dim3(NWG), dim3(NTHR),
                               args, 0, stream);

    dim3 blk(256);
    head_gemm<1><<<dim3(512, 7), blk, 0, stream>>>(hc,   W1c, b1c, hid1, nullptr, 448);
    head_gemm<0><<<dim3(512, 4), blk, 0, stream>>>(hid1, W2c, b2c, nullptr, outc, 256);
    head_gemm<1><<<dim3(512, 7), blk, 0, stream>>>(hc,   W1f, b1f, hid1, nullptr, 448);
    head_gemm<0><<<dim3(512, 4), blk, 0, stream>>>(hid1, W2f, b2f, nullptr, outf, 256);
}